// Round 8
// baseline (276.950 us; speedup 1.0000x reference)
//
#include <hip/hip_runtime.h>
#include <hip/hip_bf16.h>

// RetinaNet heads on MI355X: implicit-GEMM bf16 MFMA conv3x3.
// Block = 128 flat output positions x 80 (padded 78) out chans; 4 waves.
// [R6: W staging LDS->VGPR. A-fragments (40 VGPR/step, identical across waves) are
//  loaded global->reg from L1/L2-resident prepacked weights, register double-buffered
//  at distance 1. Deletes stageW + all per-step barriers: only 2 barriers/chunk around
//  stageX (8 total vs 36). LDS 32KB (X only). R5's regression showed occupancy is
//  grid-limited (2.67 blk/CU) -> win must come from intra-wave ILP, not buffering.]
// [R7: resubmission — round 7 bench was GPUAcquisitionTimeout, no signal]

typedef float  f32x4  __attribute__((ext_vector_type(4)));
typedef short  bf16x8 __attribute__((ext_vector_type(8)));
typedef int    i32x4  __attribute__((ext_vector_type(4)));

#define TOTAL_ANCH 32760            // 6 * sum(HW)
#define BBOX_TOTAL 2096640          // 16*4*32760
#define PW_BYTES   1474560          // 2 heads * 36 blocks * 10240 B
#define NB_MAIN    683

// f32 -> bf16 round-to-nearest-even (matches __float2bfloat16 for non-NaN)
__device__ __forceinline__ unsigned short f2bf(float f) {
    unsigned u = __float_as_uint(f);
    return (unsigned short)((u + 0x7FFFu + ((u >> 16) & 1u)) >> 16);
}

__device__ __forceinline__ unsigned pack2(float a, float b) {
    return (unsigned)f2bf(a) | ((unsigned)f2bf(b) << 16);
}

// ---------------- prepack: weights -> bf16, layout [head][chunk][kh][kw][o:80][b:8][e:8]
// (no swizzle: A-fragments are read straight from global). Bias fp32 [head][80].
__global__ void retina_prepack(
    const float* __restrict__ wr1, const float* __restrict__ br1,
    const float* __restrict__ wc1, const float* __restrict__ bc1,
    const float* __restrict__ wr2, const float* __restrict__ br2,
    const float* __restrict__ wc2, const float* __restrict__ bc2,
    unsigned short* __restrict__ PW, float* __restrict__ PB)
{
    int g = blockIdx.x * 256 + threadIdx.x;
    if (g < 737280) {
        int e = g & 7;
        int b = (g >> 3) & 7;
        int q = g >> 6;            // (((head*4+chunk)*3+kh)*3+kw)*80 + o
        int o = q % 80;
        int rest = q / 80;
        int kw = rest % 3; rest /= 3;
        int kh = rest % 3; rest /= 3;
        int chunk = rest & 3;
        int head  = rest >> 2;
        float v = 0.f;
        if (o < 78) {
            int c = (chunk << 6) + (b << 3) + e;
            const float* wsrc; int oo;
            if (o < 24) { wsrc = head ? wr2 : wr1; oo = o; }
            else        { wsrc = head ? wc2 : wc1; oo = o - 24; }
            v = wsrc[((oo * 256 + c) * 3 + kh) * 3 + kw];
        }
        PW[g] = f2bf(v);
    }
    if (g < 160) {
        int head = g / 80, o = g % 80;
        float bv = 0.f;
        if (o < 24)      bv = (head ? br2 : br1)[o];
        else if (o < 78) bv = (head ? bc2 : bc1)[o - 24];
        PB[g] = bv;
    }
}

// ---------------- main conv kernel
__global__ __launch_bounds__(256, 2) void retina_main(
    const float* __restrict__ f0, const float* __restrict__ f1,
    const float* __restrict__ f2, const float* __restrict__ f3,
    const float* __restrict__ f4, const float* __restrict__ f5,
    const unsigned short* __restrict__ PW, const float* __restrict__ PB,
    float* __restrict__ out)
{
    // X region only: 256 rows x 128 B (rows = slot*W + w, 64 bf16 chans, XOR-swizzled 16B blocks)
    __shared__ __align__(16) char lds[32768];

    const int tid = threadIdx.x;
    const int bid = blockIdx.x;

    int lvl, tile;
    if      (bid < 512) { lvl = 0; tile = bid;       }
    else if (bid < 640) { lvl = 1; tile = bid - 512; }
    else if (bid < 672) { lvl = 2; tile = bid - 640; }
    else if (bid < 680) { lvl = 3; tile = bid - 672; }
    else if (bid < 682) { lvl = 4; tile = bid - 680; }
    else                { lvl = 5; tile = 0;         }

    const int logW  = 6 - lvl;          // H == W per level
    const int W     = 1 << logW;
    const int H     = W;
    const int logHW = 2 * logW;
    const int HW    = 1 << logHW;
    const int NHW   = 16 << logHW;

    const int nrowsTab[6] = {4, 6, 10, 18, 34, 34};          // tile rows + 2 halo
    const int offlTab[6]  = {0, 24576, 30720, 32256, 32640, 32736};
    const int S    = nrowsTab[lvl];
    const int offl = offlTab[lvl];
    const float* x = (lvl == 0) ? f0 : (lvl == 1) ? f1 : (lvl == 2) ? f2
                   : (lvl == 3) ? f3 : (lvl == 4) ? f4 : f5;
    const int head = (lvl < 2) ? 0 : 1;

    const int p0 = tile << 7;           // first flat position of tile
    const int r0 = p0 >> logW;          // first flat row

    const int l   = tid & 63;
    const int wv  = tid >> 6;
    const int lg  = l >> 4;
    const int l16 = l & 15;

    int rlocal[2], wpos[2], hrow[2];
    #pragma unroll
    for (int nt = 0; nt < 2; ++nt) {
        int tpos   = wv * 32 + nt * 16 + l16;
        rlocal[nt] = tpos >> logW;
        wpos[nt]   = tpos & (W - 1);
        hrow[nt]   = (r0 + rlocal[nt]) & (H - 1);
    }

    // hoisted B-read byte offsets (bofs1 = bofs0 ^ 64) + packed ok-mask, per (nt,t9)
    int bofs0[2][9];
    unsigned okb = 0;
    #pragma unroll
    for (int nt = 0; nt < 2; ++nt) {
        #pragma unroll
        for (int t9 = 0; t9 < 9; ++t9) {
            int kh = t9 / 3, kw = t9 % 3;
            int wp = wpos[nt] + kw - 1;
            bool ok = ((unsigned)(hrow[nt] + kh - 1) < (unsigned)H)
                   && ((unsigned)wp < (unsigned)W);
            okb |= (unsigned)ok << (nt * 9 + t9);
            int wc = wp < 0 ? 0 : (wp >= W ? W - 1 : wp);
            int rowidx = ((rlocal[nt] + kh) << logW) + wc;
            int rsw = rowidx & 7;
            bofs0[nt][t9] = rowidx * 128 + ((lg ^ rsw) << 4);
        }
    }

    f32x4 acc[5][2];
    {
        f32x4 zf = {0.f, 0.f, 0.f, 0.f};
        #pragma unroll
        for (int m = 0; m < 5; ++m) { acc[m][0] = zf; acc[m][1] = zf; }
    }

    const char* pwbase = (const char*)PW + (size_t)head * 368640;   // 36 * 10240
    // per-lane A base: o = m*16 + l16 rows of 128 B, k-half lg
    const char* abase  = pwbase + l16 * 128 + lg * 16;

    // load the 10 A fragments (5 M-tiles x 2 k-halves) for one K-step into registers
    auto loadA = [&](int cidx, bf16x8* A) {
        const char* p = abase + (size_t)cidx * 10240;
        #pragma unroll
        for (int m = 0; m < 5; ++m) {
            A[2 * m]     = *(const bf16x8*)(p + m * 2048);
            A[2 * m + 1] = *(const bf16x8*)(p + m * 2048 + 64);
        }
    };

    // stage one channel-chunk of input rows [r0-1 .. r0+S-2] into X region (bf16, swizzled)
    auto stageX = [&](int chunk) {
        const int items = S << (logW + 3);          // S * 8 blocks * W
        for (int e = tid; e < items; e += 256) {
            int w = e & (W - 1);
            int b = (e >> logW) & 7;
            int s = e >> (logW + 3);
            int vr = r0 - 1 + s;
            i32x4 val = {0, 0, 0, 0};
            if ((unsigned)vr < (unsigned)(16 << logW)) {
                int n  = vr >> logW;
                int h  = vr & (H - 1);
                int c0 = (chunk << 6) + (b << 3);
                const float* src = x + (size_t)(((n << 8) + c0) << logHW) + (h << logW) + w;
                float v0 = src[0];            float v1 = src[(size_t)HW];
                float v2 = src[(size_t)2*HW]; float v3 = src[(size_t)3*HW];
                float v4 = src[(size_t)4*HW]; float v5 = src[(size_t)5*HW];
                float v6 = src[(size_t)6*HW]; float v7 = src[(size_t)7*HW];
                val[0] = (int)pack2(v0, v1);
                val[1] = (int)pack2(v2, v3);
                val[2] = (int)pack2(v4, v5);
                val[3] = (int)pack2(v6, v7);
            }
            int rowidx = (s << logW) + w;
            int boff   = rowidx * 128 + ((b ^ (rowidx & 7)) << 4);
            *(i32x4*)(lds + boff) = val;
        }
    };

    // prologue: issue A(0) loads first (covered by stageX latency), then X chunk0
    bf16x8 Ac[10];
    loadA(0, Ac);
    stageX(0);
    __syncthreads();

    for (int chunk = 0; chunk < 4; ++chunk) {
        #pragma unroll
        for (int t9 = 0; t9 < 9; ++t9) {
            const bool haveN = (t9 < 8) || (chunk < 3);
            bf16x8 An[10];
            if (haveN) loadA(chunk * 9 + t9 + 1, An);   // prefetch next K-step's A

            // B fragments from X (hoisted offsets), masked
            bf16x8 bfr[2][2];
            #pragma unroll
            for (int nt = 0; nt < 2; ++nt) {
                int o0 = bofs0[nt][t9];
                bfr[nt][0] = *(const bf16x8*)(lds + o0);
                bfr[nt][1] = *(const bf16x8*)(lds + (o0 ^ 64));
                if (!((okb >> (nt * 9 + t9)) & 1u)) {
                    bf16x8 z = {0, 0, 0, 0, 0, 0, 0, 0};
                    bfr[nt][0] = z;
                    bfr[nt][1] = z;
                }
            }

            // 20 MFMAs: 5 M-tiles x 2 N-tiles x K=64 (2 halves of 32)
            #pragma unroll
            for (int m = 0; m < 5; ++m) {
                acc[m][0] = __builtin_amdgcn_mfma_f32_16x16x32_bf16(Ac[2*m],   bfr[0][0], acc[m][0], 0, 0, 0);
                acc[m][0] = __builtin_amdgcn_mfma_f32_16x16x32_bf16(Ac[2*m+1], bfr[0][1], acc[m][0], 0, 0, 0);
                acc[m][1] = __builtin_amdgcn_mfma_f32_16x16x32_bf16(Ac[2*m],   bfr[1][0], acc[m][1], 0, 0, 0);
                acc[m][1] = __builtin_amdgcn_mfma_f32_16x16x32_bf16(Ac[2*m+1], bfr[1][1], acc[m][1], 0, 0, 0);
            }

            if (haveN) {
                #pragma unroll
                for (int i = 0; i < 10; ++i) Ac[i] = An[i];
            }
        }
        if (chunk < 3) {
            __syncthreads();            // all waves done reading X(chunk)
            stageX(chunk + 1);
            __syncthreads();
        }
    }

    // epilogue: bias + scatter to reshape/concat layout
    const float* bias = PB + head * 80;
    #pragma unroll
    for (int nt = 0; nt < 2; ++nt) {
        int pos = p0 + wv * 32 + nt * 16 + l16;
        if (pos >= NHW) continue;                   // only level 5 partial tile
        int n   = pos >> logHW;
        int rem = pos & (HW - 1);
        int base0 = offl + rem;
        #pragma unroll
        for (int m = 0; m < 5; ++m) {
            #pragma unroll
            for (int r = 0; r < 4; ++r) {
                int o = m * 16 + (l >> 4) * 4 + r;
                if (o < 78) {
                    float v = acc[m][nt][r] + bias[o];
                    int idx;
                    if (o < 24) {
                        int g = o / 6, a = o - g * 6;
                        idx = (n * 4 + g) * TOTAL_ANCH + base0 + (a << logHW);
                    } else {
                        int cc = o - 24;
                        int k = cc / 6, a = cc - k * 6;
                        idx = BBOX_TOTAL + (n * 9 + k) * TOTAL_ANCH + base0 + (a << logHW);
                    }
                    out[idx] = v;
                }
            }
        }
    }
}

extern "C" void kernel_launch(void* const* d_in, const int* in_sizes, int n_in,
                              void* d_out, int out_size, void* d_ws, size_t ws_size,
                              hipStream_t stream) {
    const float* f0  = (const float*)d_in[0];
    const float* f1  = (const float*)d_in[1];
    const float* f2  = (const float*)d_in[2];
    const float* f3  = (const float*)d_in[3];
    const float* f4  = (const float*)d_in[4];
    const float* f5  = (const float*)d_in[5];
    const float* wr1 = (const float*)d_in[6];
    const float* br1 = (const float*)d_in[7];
    const float* wc1 = (const float*)d_in[8];
    const float* bc1 = (const float*)d_in[9];
    const float* wr2 = (const float*)d_in[10];
    const float* br2 = (const float*)d_in[11];
    const float* wc2 = (const float*)d_in[12];
    const float* bc2 = (const float*)d_in[13];

    unsigned short* PW = (unsigned short*)d_ws;
    float*          PB = (float*)((char*)d_ws + PW_BYTES);

    retina_prepack<<<2880, 256, 0, stream>>>(wr1, br1, wc1, bc1, wr2, br2, wc2, bc2, PW, PB);
    retina_main<<<NB_MAIN, 256, 0, stream>>>(f0, f1, f2, f3, f4, f5, PW, PB, (float*)d_out);
}

// Round 10
// 208.942 us; speedup vs baseline: 1.3255x; 1.3255x over previous
//
#include <hip/hip_runtime.h>
#include <hip/hip_bf16.h>

// RetinaNet heads on MI355X: implicit-GEMM bf16 MFMA conv3x3.
// Block = 128 flat output positions x 80 (padded 78) out chans; 4 waves, 256 thr.
// [R8: K-split x N-grow. Wave wv: position-half (wv&1) x k-half (wv>>1) of each
//  64-chan chunk -> per wave-step 5 A + 4 B ds_read_b128 for 20 MFMA (was 14/20).
//  Block LDS read traffic x0.64 (A-redundancy halved). W via global_load_lds dbuf
//  (R4 structure, per-step barrier). Final cross-wave k-half reduction via LDS.
//  R6 lesson: global->reg A prefetch collapses (compiler sinks loads, vmcnt(0)
//  stall/step, 171us). R5 lesson: >53KB LDS kills occupancy (2 blk/CU, 90us).]
// [R9: resubmission — round 9 bench was GPUAcquisitionTimeout, no signal]

typedef float  f32x4  __attribute__((ext_vector_type(4)));
typedef short  bf16x8 __attribute__((ext_vector_type(8)));
typedef int    i32x4  __attribute__((ext_vector_type(4)));

#define TOTAL_ANCH 32760            // 6 * sum(HW)
#define BBOX_TOTAL 2096640          // 16*4*32760
#define PW_BYTES   1474560          // 2 heads * 36 blocks * 10240 B
#define NB_MAIN    683

// f32 -> bf16 RNE via hardware convert
__device__ __forceinline__ unsigned short f2bf(float f) {
    __hip_bfloat16 h = __float2bfloat16(f);
    unsigned short u;
    __builtin_memcpy(&u, &h, 2);
    return u;
}

__device__ __forceinline__ unsigned pack2(float a, float b) {
    return (unsigned)f2bf(a) | ((unsigned)f2bf(b) << 16);
}

// async global->LDS, 16 B per lane; LDS dest = wave-uniform base + lane*16
__device__ __forceinline__ void gload16(const void* g, void* l) {
    __builtin_amdgcn_global_load_lds(
        (const __attribute__((address_space(1))) void*)g,
        (__attribute__((address_space(3))) void*)l, 16, 0, 0);
}

// ---------------- prepack: weights -> bf16, layout [head][chunk][kh][kw][o:80][b:8][e:8]
// with per-row pre-swizzle b_stored = b_logical ^ (o&7) (A read from LDS again).
__global__ void retina_prepack(
    const float* __restrict__ wr1, const float* __restrict__ br1,
    const float* __restrict__ wc1, const float* __restrict__ bc1,
    const float* __restrict__ wr2, const float* __restrict__ br2,
    const float* __restrict__ wc2, const float* __restrict__ bc2,
    unsigned short* __restrict__ PW, float* __restrict__ PB)
{
    int g = blockIdx.x * 256 + threadIdx.x;
    if (g < 737280) {
        int e = g & 7;
        int b = (g >> 3) & 7;
        int q = g >> 6;            // (((head*4+chunk)*3+kh)*3+kw)*80 + o
        int o = q % 80;
        int rest = q / 80;
        int kw = rest % 3; rest /= 3;
        int kh = rest % 3; rest /= 3;
        int chunk = rest & 3;
        int head  = rest >> 2;
        float v = 0.f;
        if (o < 78) {
            int c = (chunk << 6) + ((b ^ (o & 7)) << 3) + e;   // pre-swizzled channel
            const float* wsrc; int oo;
            if (o < 24) { wsrc = head ? wr2 : wr1; oo = o; }
            else        { wsrc = head ? wc2 : wc1; oo = o - 24; }
            v = wsrc[((oo * 256 + c) * 3 + kh) * 3 + kw];
        }
        PW[g] = f2bf(v);
    }
    if (g < 160) {
        int head = g / 80, o = g % 80;
        float bv = 0.f;
        if (o < 24)      bv = (head ? br2 : br1)[o];
        else if (o < 78) bv = (head ? bc2 : bc1)[o - 24];
        PB[g] = bv;
    }
}

// ---------------- main conv kernel
__global__ __launch_bounds__(256, 2) void retina_main(
    const float* __restrict__ f0, const float* __restrict__ f1,
    const float* __restrict__ f2, const float* __restrict__ f3,
    const float* __restrict__ f4, const float* __restrict__ f5,
    const unsigned short* __restrict__ PW, const float* __restrict__ PB,
    float* __restrict__ out)
{
    // X: 256 rows x 128 B (XOR-swizzled 16B blocks). W: 2 x 10240 B dbuf.
    __shared__ __align__(16) char lds[32768 + 2 * 10240];

    const int tid = threadIdx.x;
    const int bid = blockIdx.x;

    int lvl, tile;
    if      (bid < 512) { lvl = 0; tile = bid;       }
    else if (bid < 640) { lvl = 1; tile = bid - 512; }
    else if (bid < 672) { lvl = 2; tile = bid - 640; }
    else if (bid < 680) { lvl = 3; tile = bid - 672; }
    else if (bid < 682) { lvl = 4; tile = bid - 680; }
    else                { lvl = 5; tile = 0;         }

    const int logW  = 6 - lvl;          // H == W per level
    const int W     = 1 << logW;
    const int H     = W;
    const int logHW = 2 * logW;
    const int HW    = 1 << logHW;
    const int NHW   = 16 << logHW;

    const int nrowsTab[6] = {4, 6, 10, 18, 34, 34};          // tile rows + 2 halo
    const int offlTab[6]  = {0, 24576, 30720, 32256, 32640, 32736};
    const int S    = nrowsTab[lvl];
    const int offl = offlTab[lvl];
    const float* x = (lvl == 0) ? f0 : (lvl == 1) ? f1 : (lvl == 2) ? f2
                   : (lvl == 3) ? f3 : (lvl == 4) ? f4 : f5;
    const int head = (lvl < 2) ? 0 : 1;

    const int p0 = tile << 7;           // first flat position of tile
    const int r0 = p0 >> logW;          // first flat row

    const int l   = tid & 63;
    const int wv  = tid >> 6;
    const int lg  = l >> 4;
    const int l16 = l & 15;
    const int ph  = wv & 1;             // position half: 64 positions
    const int kh2 = wv >> 1;            // k-half of each 64-chan chunk
    const int lgh = lg ^ (kh2 << 2);    // logical 16B block for this k-half

    int slotbase[4], wpos[4], hrow[4];
    #pragma unroll
    for (int nt = 0; nt < 4; ++nt) {
        int tpos     = ph * 64 + nt * 16 + l16;
        int rl       = tpos >> logW;
        slotbase[nt] = rl << logW;
        wpos[nt]     = tpos & (W - 1);
        hrow[nt]     = (r0 + rl) & (H - 1);
    }

    // packed validity mask per (nt, t9)
    unsigned long long okb = 0;
    #pragma unroll
    for (int nt = 0; nt < 4; ++nt) {
        #pragma unroll
        for (int t9 = 0; t9 < 9; ++t9) {
            int kh = t9 / 3, kw = t9 % 3;
            bool ok = ((unsigned)(hrow[nt] + kh - 1) < (unsigned)H)
                   && ((unsigned)(wpos[nt] + kw - 1) < (unsigned)W);
            okb |= (unsigned long long)ok << (nt * 9 + t9);
        }
    }

    f32x4 acc[5][4];
    {
        f32x4 zf = {0.f, 0.f, 0.f, 0.f};
        #pragma unroll
        for (int m = 0; m < 5; ++m)
            #pragma unroll
            for (int nt = 0; nt < 4; ++nt) acc[m][nt] = zf;
    }

    // A-fragment byte offset within a W buffer (row o = m*16+l16, block lgh, swizzled)
    const int aoffB = l16 * 128 + ((lgh ^ (l16 & 7)) << 4);

    const char* pwbase = (const char*)PW + (size_t)head * 368640;   // 36 * 10240

    // async W stage: wave wv covers bytes [wv*2560, +2560) of the 10240-B block
    auto stageW = [&](int cidx, int buf) {
        const char* src = pwbase + (size_t)cidx * 10240 + wv * 2560 + l * 16;
        char*       dst = lds + 32768 + buf * 10240 + wv * 2560;
        gload16(src,        dst);
        gload16(src + 1024, dst + 1024);
        if (l < 32) gload16(src + 2048, dst + 2048);
    };

    // stage one channel-chunk of input rows [r0-1 .. r0+S-2] into X (bf16, swizzled)
    auto stageX = [&](int chunk) {
        const int items = S << (logW + 3);          // S * 8 blocks * W
        for (int e = tid; e < items; e += 256) {
            int w = e & (W - 1);
            int b = (e >> logW) & 7;
            int s = e >> (logW + 3);
            int vr = r0 - 1 + s;
            i32x4 val = {0, 0, 0, 0};
            if ((unsigned)vr < (unsigned)(16 << logW)) {
                int n  = vr >> logW;
                int h  = vr & (H - 1);
                int c0 = (chunk << 6) + (b << 3);
                const float* src = x + (size_t)(((n << 8) + c0) << logHW) + (h << logW) + w;
                float v0 = src[0];            float v1 = src[(size_t)HW];
                float v2 = src[(size_t)2*HW]; float v3 = src[(size_t)3*HW];
                float v4 = src[(size_t)4*HW]; float v5 = src[(size_t)5*HW];
                float v6 = src[(size_t)6*HW]; float v7 = src[(size_t)7*HW];
                val[0] = (int)pack2(v0, v1);
                val[1] = (int)pack2(v2, v3);
                val[2] = (int)pack2(v4, v5);
                val[3] = (int)pack2(v6, v7);
            }
            int rowidx = (s << logW) + w;
            int boff   = rowidx * 128 + ((b ^ (rowidx & 7)) << 4);
            *(i32x4*)(lds + boff) = val;
        }
    };

    // prologue
    stageW(0, 0);
    stageX(0);
    __syncthreads();

    for (int chunk = 0; chunk < 4; ++chunk) {
        #pragma unroll
        for (int t9 = 0; t9 < 9; ++t9) {
            const int cidx = chunk * 9 + t9;
            const int kh = t9 / 3, kw = t9 % 3;

            // async-prefetch next W block (lands by this step's end barrier)
            if (cidx + 1 < 36) stageW(cidx + 1, (cidx + 1) & 1);

            // A fragments for this k-half (5 m-tiles)
            const char* wb = lds + 32768 + (cidx & 1) * 10240;
            bf16x8 Afr[5];
            #pragma unroll
            for (int m = 0; m < 5; ++m)
                Afr[m] = *(const bf16x8*)(wb + m * 2048 + aoffB);

            // 4 N-tiles x 5 M-tiles, one k-half each
            #pragma unroll
            for (int nt = 0; nt < 4; ++nt) {
                int rowidx = slotbase[nt] + (kh << logW) + ((wpos[nt] + kw - 1) & (W - 1));
                int boff   = rowidx * 128 + ((lgh ^ (rowidx & 7)) << 4);
                bf16x8 b = *(const bf16x8*)(lds + boff);
                if (!((okb >> (nt * 9 + t9)) & 1ull)) {
                    bf16x8 z = {0, 0, 0, 0, 0, 0, 0, 0};
                    b = z;
                }
                #pragma unroll
                for (int m = 0; m < 5; ++m)
                    acc[m][nt] = __builtin_amdgcn_mfma_f32_16x16x32_bf16(Afr[m], b, acc[m][nt], 0, 0, 0);
            }
            __syncthreads();   // publishes next W buffer (drains DMA), releases current
        }
        if (chunk < 3) {
            stageX(chunk + 1);
            __syncthreads();
        }
    }

    // cross-wave k-half reduction: waves 2,3 dump acc; waves 0,1 add
    if (wv >= 2) {
        char* red = lds + (wv - 2) * 20480;
        #pragma unroll
        for (int m = 0; m < 5; ++m)
            #pragma unroll
            for (int nt = 0; nt < 4; ++nt)
                *(f32x4*)(red + (m * 4 + nt) * 1024 + l * 16) = acc[m][nt];
    }
    __syncthreads();

    if (wv < 2) {
        const char* red = lds + wv * 20480;
        #pragma unroll
        for (int m = 0; m < 5; ++m)
            #pragma unroll
            for (int nt = 0; nt < 4; ++nt)
                acc[m][nt] += *(const f32x4*)(red + (m * 4 + nt) * 1024 + l * 16);

        // epilogue: bias + scatter to reshape/concat layout
        const float* bias = PB + head * 80;
        #pragma unroll
        for (int nt = 0; nt < 4; ++nt) {
            int pos = p0 + wv * 64 + nt * 16 + l16;
            if (pos >= NHW) continue;               // only level 5 partial tile
            int n   = pos >> logHW;
            int rem = pos & (HW - 1);
            int base0 = offl + rem;
            #pragma unroll
            for (int m = 0; m < 5; ++m) {
                #pragma unroll
                for (int r = 0; r < 4; ++r) {
                    int o = m * 16 + lg * 4 + r;
                    if (o < 78) {
                        float v = acc[m][nt][r] + bias[o];
                        int idx;
                        if (o < 24) {
                            int g = o / 6, a = o - g * 6;
                            idx = (n * 4 + g) * TOTAL_ANCH + base0 + (a << logHW);
                        } else {
                            int cc = o - 24;
                            int k = cc / 6, a = cc - k * 6;
                            idx = BBOX_TOTAL + (n * 9 + k) * TOTAL_ANCH + base0 + (a << logHW);
                        }
                        out[idx] = v;
                    }
                }
            }
        }
    }
}

extern "C" void kernel_launch(void* const* d_in, const int* in_sizes, int n_in,
                              void* d_out, int out_size, void* d_ws, size_t ws_size,
                              hipStream_t stream) {
    const float* f0  = (const float*)d_in[0];
    const float* f1  = (const float*)d_in[1];
    const float* f2  = (const float*)d_in[2];
    const float* f3  = (const float*)d_in[3];
    const float* f4  = (const float*)d_in[4];
    const float* f5  = (const float*)d_in[5];
    const float* wr1 = (const float*)d_in[6];
    const float* br1 = (const float*)d_in[7];
    const float* wc1 = (const float*)d_in[8];
    const float* bc1 = (const float*)d_in[9];
    const float* wr2 = (const float*)d_in[10];
    const float* br2 = (const float*)d_in[11];
    const float* wc2 = (const float*)d_in[12];
    const float* bc2 = (const float*)d_in[13];

    unsigned short* PW = (unsigned short*)d_ws;
    float*          PB = (float*)((char*)d_ws + PW_BYTES);

    retina_prepack<<<2880, 256, 0, stream>>>(wr1, br1, wc1, bc1, wr2, br2, wc2, bc2, PW, PB);
    retina_main<<<NB_MAIN, 256, 0, stream>>>(f0, f1, f2, f3, f4, f5, PW, PB, (float*)d_out);
}